// Round 1
// baseline (565.312 us; speedup 1.0000x reference)
//
#include <hip/hip_runtime.h>

// GAT forward, MI355X. Sizes fixed by the reference:
// B=4, N=2048, NFEAT=128, NHID=64, NCLASS=32, NHEADS=8, alpha=0.2
//
// Pipeline:
//  K1 pack_mask : adj(268MB i32) -> 2MB bitmask        (HBM-bound, ~43us floor)
//  K2 wh        : Wh[b,h] = x[b] @ W[h]  (fp32 tile GEMM)
//  K2b repack<64>: Wh -> bf16 MFMA-B-fragment order
//  K3 f12       : f1/f2 = Wh . a1/a2  (wave reduce)
//  K4 attn1     : MFMA flash-style: w_ij=mask?exp(LR(f1+f2)):0 generated
//                 per-lane directly in A-frag layout; no LDS, no barriers.
//                 out h1[b,n,h*64+d] = elu((w @ Wh)/Z)
//  K5 ogemm     : Wh2 = h1 @ Wo (fp32) + g1/g2 epilogue
//  K5b repack<32>: Wh2 -> bf16 frag order
//  K6 attn2     : same MFMA trick, j-split across 4 waves + LDS combine
//
// Softmax max-subtraction skipped (scores ~N(0,1.3^2); exp() safe in fp32 by
// huge margin; softmax is shift-invariant). Z accumulated from bf16-rounded w
// so numerator/denominator are consistent.

typedef short  short8  __attribute__((ext_vector_type(8)));
typedef float  float4_ __attribute__((ext_vector_type(4)));

static __device__ __forceinline__ unsigned short f2bf(float f) {
  unsigned u = __float_as_uint(f);
  u += 0x7fffu + ((u >> 16) & 1u);          // RNE
  return (unsigned short)(u >> 16);
}
static __device__ __forceinline__ float bf2f(unsigned short s) {
  return __uint_as_float(((unsigned)s) << 16);
}

// ---------------- K1: adj -> bitmask (word w bit l <=> column w*64+l) -------
__global__ __launch_bounds__(256) void k_pack_mask(
    const int* __restrict__ adj, unsigned long long* __restrict__ maskb) {
  const int t = threadIdx.x;
  const int lane = t & 63, wid = t >> 6;
  const int s = lane & 15;
  const long long row0 = (long long)blockIdx.x * 4;
  for (int rr = 0; rr < 4; ++rr) {
    const long long row = row0 + rr;
    const int4* src = (const int4*)(adj + row * 2048);
    #pragma unroll
    for (int c = 0; c < 2; ++c) {
      int4 v = src[c * 256 + t];
      unsigned nib = (v.x != 0 ? 1u : 0u) | (v.y != 0 ? 2u : 0u) |
                     (v.z != 0 ? 4u : 0u) | (v.w != 0 ? 8u : 0u);
      unsigned lo = (s < 8) ? (nib << (s * 4)) : 0u;
      unsigned hi = (s >= 8) ? (nib << ((s - 8) * 4)) : 0u;
      #pragma unroll
      for (int off = 1; off < 16; off <<= 1) {
        lo |= __shfl_xor(lo, off);
        hi |= __shfl_xor(hi, off);
      }
      if (s == 0) {
        int word = c * 16 + wid * 4 + (lane >> 4);
        maskb[row * 32 + word] = ((unsigned long long)hi << 32) | (unsigned long long)lo;
      }
    }
  }
}

// ---------------- K2: Wh = x @ W  (fp32, 64x64 tile, k=128) -----------------
__global__ __launch_bounds__(256) void k_wh(
    const float* __restrict__ x, const float* __restrict__ Wm, float* __restrict__ Wh) {
  __shared__ float xs[64 * 65];
  __shared__ float wss[128 * 64];
  const int bh = blockIdx.y, b = bh >> 3, h = bh & 7;
  const int i0 = blockIdx.x * 64;
  const int t = threadIdx.x;
  const float* xp = x + ((long long)b * 2048 + i0) * 128;
  const float* wp = Wm + (long long)h * (128 * 64);
  #pragma unroll
  for (int f = 0; f < 8; ++f)
    ((float4*)wss)[f * 256 + t] = ((const float4*)wp)[f * 256 + t];
  const int tx = t & 15, ty = t >> 4;
  float acc[4][4] = {};
  for (int kc = 0; kc < 2; ++kc) {
    __syncthreads();
    #pragma unroll
    for (int f = 0; f < 4; ++f) {
      int ff = f * 256 + t;
      int i = ff >> 4, kq = ff & 15;
      float4 v = *(const float4*)(xp + (long long)i * 128 + kc * 64 + kq * 4);
      int base = i * 65 + kq * 4;
      xs[base] = v.x; xs[base + 1] = v.y; xs[base + 2] = v.z; xs[base + 3] = v.w;
    }
    __syncthreads();
    for (int k = 0; k < 64; ++k) {
      float4 wv = *(const float4*)&wss[(kc * 64 + k) * 64 + tx * 4];
      float xv0 = xs[(ty * 4 + 0) * 65 + k];
      float xv1 = xs[(ty * 4 + 1) * 65 + k];
      float xv2 = xs[(ty * 4 + 2) * 65 + k];
      float xv3 = xs[(ty * 4 + 3) * 65 + k];
      acc[0][0] += xv0 * wv.x; acc[0][1] += xv0 * wv.y; acc[0][2] += xv0 * wv.z; acc[0][3] += xv0 * wv.w;
      acc[1][0] += xv1 * wv.x; acc[1][1] += xv1 * wv.y; acc[1][2] += xv1 * wv.z; acc[1][3] += xv1 * wv.w;
      acc[2][0] += xv2 * wv.x; acc[2][1] += xv2 * wv.y; acc[2][2] += xv2 * wv.z; acc[2][3] += xv2 * wv.w;
      acc[3][0] += xv3 * wv.x; acc[3][1] += xv3 * wv.y; acc[3][2] += xv3 * wv.z; acc[3][3] += xv3 * wv.w;
    }
  }
  float* op = Wh + (((long long)bh * 2048) + i0 + ty * 4) * 64 + tx * 4;
  #pragma unroll
  for (int ii = 0; ii < 4; ++ii) {
    float4 v = make_float4(acc[ii][0], acc[ii][1], acc[ii][2], acc[ii][3]);
    *(float4*)(op + (long long)ii * 64) = v;
  }
}

// ------- K2b/K5b: fp32 [G][2048][D] -> bf16 MFMA B-fragment order -----------
// dst element order: [g][jc(32)][ks(2)][nt(D/16)][lane(64)][jj(8)]
// where B[k=(lane>>4)*8+jj][n=lane&15] = src[jc*64+ks*32+(lane>>4)*8+jj][nt*16+(lane&15)]
template <int D>
__global__ __launch_bounds__(256) void k_repack(
    const float* __restrict__ src, short* __restrict__ dst) {
  const long long T = (long long)blockIdx.x * 256 + threadIdx.x;
  const int lane = (int)(T & 63);
  long long r = T >> 6;
  constexpr int NT = D / 16;
  const int nt = (int)(r & (NT - 1)); r >>= (NT == 4 ? 2 : 1);
  const int ks = (int)(r & 1); r >>= 1;
  const int jc = (int)(r & 31);
  const long long g = r >> 5;
  const int d = nt * 16 + (lane & 15);
  const long long jb = (long long)jc * 64 + ks * 32 + ((lane >> 4) * 8);
  const float* sp = src + (g * 2048 + jb) * D + d;
  short8 o;
  #pragma unroll
  for (int jj = 0; jj < 8; ++jj) o[jj] = (short)f2bf(sp[(long long)jj * D]);
  *(short8*)(dst + T * 8) = o;
}

// ---------------- K3: f1/f2 = Wh . a1/a2 (one wave per row) -----------------
__global__ __launch_bounds__(256) void k_f12(
    const float* __restrict__ Wh, const float* __restrict__ a1,
    const float* __restrict__ a2, float* __restrict__ f1, float* __restrict__ f2) {
  const long long row = ((long long)blockIdx.x * 256 + threadIdx.x) >> 6;
  const int lane = threadIdx.x & 63;
  const int h = (int)((row >> 11) & 7);
  float v = Wh[row * 64 + lane];
  float p1 = v * a1[h * 64 + lane];
  float p2 = v * a2[h * 64 + lane];
  #pragma unroll
  for (int off = 32; off; off >>= 1) {
    p1 += __shfl_xor(p1, off);
    p2 += __shfl_xor(p2, off);
  }
  if (lane == 0) { f1[row] = p1; f2[row] = p2; }
}

// ---------------- K4: layer-1 attention, MFMA, no LDS/barriers --------------
__global__ __launch_bounds__(256) void k_attn1(
    const short* __restrict__ whf, const float* __restrict__ f1v,
    const float* __restrict__ f2v, const unsigned long long* __restrict__ maskb,
    float* __restrict__ h1) {
  const int bh = blockIdx.y, b = bh >> 3, hh = bh & 7;
  const int t = threadIdx.x;
  const int lane = t & 63, wid = t >> 6;
  const int cl = lane & 15, q = lane >> 4;
  const long long i_g = (long long)blockIdx.x * 64 + wid * 16 + cl;
  const float f1i = f1v[(long long)bh * 2048 + i_g];
  const unsigned long long* mp = maskb + ((long long)b * 2048 + i_g) * 32;
  const float* f2b = f2v + (long long)bh * 2048;
  const short* whfb = whf + (long long)bh * 131072;
  float4_ acc0 = {0.f, 0.f, 0.f, 0.f}, acc1 = acc0, acc2 = acc0, acc3 = acc0;
  float zpart = 0.f;
  for (int jc = 0; jc < 32; ++jc) {
    const unsigned long long mw = mp[jc];
    #pragma unroll
    for (int ks = 0; ks < 2; ++ks) {
      const unsigned mb = (unsigned)(mw >> (ks * 32 + q * 8)) & 0xffu;
      const float* fp = f2b + jc * 64 + ks * 32 + q * 8;
      const float4 fa = *(const float4*)fp;
      const float4 fb = *(const float4*)(fp + 4);
      const float f2j[8] = {fa.x, fa.y, fa.z, fa.w, fb.x, fb.y, fb.z, fb.w};
      short8 af;
      #pragma unroll
      for (int jj = 0; jj < 8; ++jj) {
        float e = f1i + f2j[jj];
        e = fmaxf(e, 0.2f * e);                       // leaky_relu
        float w = ((mb >> jj) & 1u) ? __expf(e) : 0.f;
        unsigned short bw = f2bf(w);
        af[jj] = (short)bw;
        zpart += bf2f(bw);                            // Z consistent with bf16 w
      }
      const short* bb = whfb + (jc * 2 + ks) * 2048 + lane * 8;
      short8 b0 = *(const short8*)(bb);
      short8 b1 = *(const short8*)(bb + 512);
      short8 b2 = *(const short8*)(bb + 1024);
      short8 b3 = *(const short8*)(bb + 1536);
      acc0 = __builtin_amdgcn_mfma_f32_16x16x32_bf16(af, b0, acc0, 0, 0, 0);
      acc1 = __builtin_amdgcn_mfma_f32_16x16x32_bf16(af, b1, acc1, 0, 0, 0);
      acc2 = __builtin_amdgcn_mfma_f32_16x16x32_bf16(af, b2, acc2, 0, 0, 0);
      acc3 = __builtin_amdgcn_mfma_f32_16x16x32_bf16(af, b3, acc3, 0, 0, 0);
    }
  }
  zpart += __shfl_xor(zpart, 16);
  zpart += __shfl_xor(zpart, 32);    // all lanes: Z for row (lane&15)
  float4_ accs[4] = {acc0, acc1, acc2, acc3};
  #pragma unroll
  for (int reg = 0; reg < 4; ++reg) {
    const int ir = q * 4 + reg;                       // C row
    const float zi = __shfl(zpart, ir);
    const float rz = 1.f / zi;
    const long long row = (long long)blockIdx.x * 64 + wid * 16 + ir;
    float* op = h1 + ((long long)b * 2048 + row) * 512 + hh * 64 + cl;
    #pragma unroll
    for (int nt = 0; nt < 4; ++nt) {
      float v = accs[nt][reg] * rz;
      v = (v > 0.f) ? v : (__expf(v) - 1.f);          // elu
      op[nt * 16] = v;
    }
  }
}

// ---------------- K5: Wh2 = h1 @ Wo + g1/g2 epilogue (fp32) -----------------
__global__ __launch_bounds__(256) void k_ogemm(
    const float* __restrict__ h1, const float* __restrict__ Wo,
    const float* __restrict__ ao1, const float* __restrict__ ao2,
    float* __restrict__ Wh2, float* __restrict__ g1, float* __restrict__ g2) {
  __shared__ float hs[64 * 65];
  __shared__ float wos[64 * 32];
  const long long r0 = (long long)blockIdx.x * 64;
  const int t = threadIdx.x;
  const int cx = t & 7, ry = t >> 3;
  float acc[2][4] = {};
  for (int kc = 0; kc < 8; ++kc) {
    __syncthreads();
    #pragma unroll
    for (int f = 0; f < 4; ++f) {
      int ff = f * 256 + t;
      int i = ff >> 4, kq = ff & 15;
      float4 v = *(const float4*)(h1 + (r0 + i) * 512 + kc * 64 + kq * 4);
      int base = i * 65 + kq * 4;
      hs[base] = v.x; hs[base + 1] = v.y; hs[base + 2] = v.z; hs[base + 3] = v.w;
    }
    #pragma unroll
    for (int f = 0; f < 2; ++f) {
      int ff = f * 256 + t;
      ((float4*)wos)[ff] = ((const float4*)(Wo + kc * (64 * 32)))[ff];
    }
    __syncthreads();
    for (int k = 0; k < 64; ++k) {
      float4 wv = *(const float4*)&wos[k * 32 + cx * 4];
      float ha = hs[(ry * 2 + 0) * 65 + k];
      float hb = hs[(ry * 2 + 1) * 65 + k];
      acc[0][0] += ha * wv.x; acc[0][1] += ha * wv.y; acc[0][2] += ha * wv.z; acc[0][3] += ha * wv.w;
      acc[1][0] += hb * wv.x; acc[1][1] += hb * wv.y; acc[1][2] += hb * wv.z; acc[1][3] += hb * wv.w;
    }
  }
  float4 v0 = make_float4(acc[0][0], acc[0][1], acc[0][2], acc[0][3]);
  float4 v1 = make_float4(acc[1][0], acc[1][1], acc[1][2], acc[1][3]);
  float* wp = Wh2 + (r0 + ry * 2) * 32 + cx * 4;
  *(float4*)wp = v0;
  *(float4*)(wp + 32) = v1;
  float4 o1 = *(const float4*)(ao1 + cx * 4);
  float4 o2 = *(const float4*)(ao2 + cx * 4);
  float p1a = v0.x * o1.x + v0.y * o1.y + v0.z * o1.z + v0.w * o1.w;
  float p1b = v1.x * o1.x + v1.y * o1.y + v1.z * o1.z + v1.w * o1.w;
  float p2a = v0.x * o2.x + v0.y * o2.y + v0.z * o2.z + v0.w * o2.w;
  float p2b = v1.x * o2.x + v1.y * o2.y + v1.z * o2.z + v1.w * o2.w;
  #pragma unroll
  for (int off = 1; off < 8; off <<= 1) {
    p1a += __shfl_xor(p1a, off);
    p1b += __shfl_xor(p1b, off);
    p2a += __shfl_xor(p2a, off);
    p2b += __shfl_xor(p2b, off);
  }
  if (cx == 0) {
    g1[r0 + ry * 2] = p1a; g1[r0 + ry * 2 + 1] = p1b;
    g2[r0 + ry * 2] = p2a; g2[r0 + ry * 2 + 1] = p2b;
  }
}

// ---------------- K6: output attention, MFMA, 4-way j-split -----------------
__global__ __launch_bounds__(256) void k_attn2(
    const short* __restrict__ whf2, const float* __restrict__ g1v,
    const float* __restrict__ g2v, const unsigned long long* __restrict__ maskb,
    float* __restrict__ outp) {
  __shared__ float accs[4][16][33];
  __shared__ float zsh[64];
  const int b = blockIdx.y;
  const long long i0 = (long long)blockIdx.x * 16;
  const int t = threadIdx.x, lane = t & 63, wid = t >> 6;
  const int cl = lane & 15, q = lane >> 4;
  const float g1i = g1v[(long long)b * 2048 + i0 + cl];
  const unsigned long long* mp = maskb + ((long long)b * 2048 + i0 + cl) * 32;
  const float* g2b = g2v + (long long)b * 2048;
  const short* wb = whf2 + (long long)b * 65536;
  float4_ acc0 = {0.f, 0.f, 0.f, 0.f}, acc1 = acc0;
  float zpart = 0.f;
  for (int c8 = 0; c8 < 8; ++c8) {
    const int jc = wid * 8 + c8;                       // each wave: 512 j's
    const unsigned long long mw = mp[jc];
    #pragma unroll
    for (int ks = 0; ks < 2; ++ks) {
      const unsigned mb = (unsigned)(mw >> (ks * 32 + q * 8)) & 0xffu;
      const float* fp = g2b + jc * 64 + ks * 32 + q * 8;
      const float4 fa = *(const float4*)fp;
      const float4 fb = *(const float4*)(fp + 4);
      const float g2j[8] = {fa.x, fa.y, fa.z, fa.w, fb.x, fb.y, fb.z, fb.w};
      short8 af;
      #pragma unroll
      for (int jj = 0; jj < 8; ++jj) {
        float e = g1i + g2j[jj];
        e = fmaxf(e, 0.2f * e);
        float w = ((mb >> jj) & 1u) ? __expf(e) : 0.f;
        unsigned short bw = f2bf(w);
        af[jj] = (short)bw;
        zpart += bf2f(bw);
      }
      const short* bb = wb + (jc * 2 + ks) * 1024 + lane * 8;
      short8 b0 = *(const short8*)bb;
      short8 b1 = *(const short8*)(bb + 512);
      acc0 = __builtin_amdgcn_mfma_f32_16x16x32_bf16(af, b0, acc0, 0, 0, 0);
      acc1 = __builtin_amdgcn_mfma_f32_16x16x32_bf16(af, b1, acc1, 0, 0, 0);
    }
  }
  zpart += __shfl_xor(zpart, 16);
  zpart += __shfl_xor(zpart, 32);
  if (q == 0) zsh[wid * 16 + cl] = zpart;
  float4_ a01[2] = {acc0, acc1};
  #pragma unroll
  for (int nt = 0; nt < 2; ++nt)
    #pragma unroll
    for (int reg = 0; reg < 4; ++reg)
      accs[wid][q * 4 + reg][nt * 16 + cl] = a01[nt][reg];
  __syncthreads();
  #pragma unroll
  for (int r = 0; r < 2; ++r) {
    int o = r * 256 + t;
    int il = o >> 5, c = o & 31;
    float s = accs[0][il][c] + accs[1][il][c] + accs[2][il][c] + accs[3][il][c];
    float Z = zsh[il] + zsh[16 + il] + zsh[32 + il] + zsh[48 + il];
    outp[((long long)b * 2048 + i0 + il) * 32 + c] = s / Z;
  }
}

// ---------------------------------------------------------------------------
extern "C" void kernel_launch(void* const* d_in, const int* in_sizes, int n_in,
                              void* d_out, int out_size, void* d_ws, size_t ws_size,
                              hipStream_t stream) {
  const float* x   = (const float*)d_in[0];
  const int*   adj = (const int*)d_in[1];
  const float* W   = (const float*)d_in[2];
  const float* a1  = (const float*)d_in[3];
  const float* a2  = (const float*)d_in[4];
  const float* Wo  = (const float*)d_in[5];
  const float* ao1 = (const float*)d_in[6];
  const float* ao2 = (const float*)d_in[7];
  float* out = (float*)d_out;
  char* ws = (char*)d_ws;

  unsigned long long* maskb = (unsigned long long*)(ws + 0);          //  2 MB
  float* Wh   = (float*)(ws + 2097152);                               // 16 MB
  short* WhF  = (short*)(ws + 18874368);                              //  8 MB bf16 frags
  float* f1   = (float*)(ws + 27262976);
  float* f2   = (float*)(ws + 27525120);
  float* h1   = (float*)(ws + 27787264);                              // 16 MB
  float* Wh2  = (float*)(ws + 44564480);                              //  1 MB
  short* Wh2F = (short*)(ws + 45613056);                              //  0.5 MB
  float* g1   = (float*)(ws + 46137344);
  float* g2   = (float*)(ws + 46170112);

  hipLaunchKernelGGL(k_pack_mask, dim3(2048), dim3(256), 0, stream, adj, maskb);
  hipLaunchKernelGGL(k_wh, dim3(32, 32), dim3(256), 0, stream, x, W, Wh);
  hipLaunchKernelGGL((k_repack<64>), dim3(2048), dim3(256), 0, stream, Wh, WhF);
  hipLaunchKernelGGL(k_f12, dim3(16384), dim3(256), 0, stream, Wh, a1, a2, f1, f2);
  hipLaunchKernelGGL(k_attn1, dim3(32, 32), dim3(256), 0, stream, WhF, f1, f2, maskb, h1);
  hipLaunchKernelGGL(k_ogemm, dim3(128), dim3(256), 0, stream, h1, Wo, ao1, ao2, Wh2, g1, g2);
  hipLaunchKernelGGL((k_repack<32>), dim3(128), dim3(256), 0, stream, Wh2, Wh2F);
  hipLaunchKernelGGL(k_attn2, dim3(128, 4), dim3(256), 0, stream, Wh2F, g1, g2, maskb, out);
}

// Round 2
// 238.491 us; speedup vs baseline: 2.3704x; 2.3704x over previous
//
#include <hip/hip_runtime.h>

// GAT forward, MI355X. Sizes fixed by the reference:
// B=4, N=2048, NFEAT=128, NHID=64, NCLASS=32, NHEADS=8, alpha=0.2
//
// Pipeline:
//  K1 pack_mask : adj(268MB i32) -> 2MB bitmask        (HBM-bound, ~43us floor)
//  K2 wh        : Wh[b,h] = x[b] @ W[h]  (fp32 tile GEMM)
//  K2b repack<64>: Wh -> bf16 MFMA-B-fragment order
//  K3 f12       : f1/f2 = Wh . a1/a2  (wave reduce)
//  K4 attn1     : MFMA flash-style: w_ij=mask?exp(LR(f1+f2)):0 generated
//                 per-lane directly in A-frag layout; no LDS, no barriers.
//                 out h1[b,n,h*64+d] = elu((w @ Wh)/Z)
//  K5 ogemm     : Wh2 = h1 @ Wo (fp32) + g1/g2 epilogue
//                 R1 rewrite: old version hit 256 VGPR + 284MB scratch spill
//                 traffic (347us). New: 32 rows/block staged in 64KB LDS,
//                 broadcast ds_read_b128, 4 acc/thread -> no spill.
//  K5b repack<32>: Wh2 -> bf16 frag order
//  K6 attn2     : same MFMA trick, j-split across 4 waves + LDS combine
//
// Softmax max-subtraction skipped (scores ~N(0,1.3^2); exp() safe in fp32 by
// huge margin; softmax is shift-invariant). Z accumulated from bf16-rounded w
// so numerator/denominator are consistent.

typedef short  short8  __attribute__((ext_vector_type(8)));
typedef float  float4_ __attribute__((ext_vector_type(4)));

static __device__ __forceinline__ unsigned short f2bf(float f) {
  unsigned u = __float_as_uint(f);
  u += 0x7fffu + ((u >> 16) & 1u);          // RNE
  return (unsigned short)(u >> 16);
}
static __device__ __forceinline__ float bf2f(unsigned short s) {
  return __uint_as_float(((unsigned)s) << 16);
}

// ---------------- K1: adj -> bitmask (word w bit l <=> column w*64+l) -------
__global__ __launch_bounds__(256) void k_pack_mask(
    const int* __restrict__ adj, unsigned long long* __restrict__ maskb) {
  const int t = threadIdx.x;
  const int lane = t & 63, wid = t >> 6;
  const int s = lane & 15;
  const long long row0 = (long long)blockIdx.x * 4;
  for (int rr = 0; rr < 4; ++rr) {
    const long long row = row0 + rr;
    const int4* src = (const int4*)(adj + row * 2048);
    #pragma unroll
    for (int c = 0; c < 2; ++c) {
      int4 v = src[c * 256 + t];
      unsigned nib = (v.x != 0 ? 1u : 0u) | (v.y != 0 ? 2u : 0u) |
                     (v.z != 0 ? 4u : 0u) | (v.w != 0 ? 8u : 0u);
      unsigned lo = (s < 8) ? (nib << (s * 4)) : 0u;
      unsigned hi = (s >= 8) ? (nib << ((s - 8) * 4)) : 0u;
      #pragma unroll
      for (int off = 1; off < 16; off <<= 1) {
        lo |= __shfl_xor(lo, off);
        hi |= __shfl_xor(hi, off);
      }
      if (s == 0) {
        int word = c * 16 + wid * 4 + (lane >> 4);
        maskb[row * 32 + word] = ((unsigned long long)hi << 32) | (unsigned long long)lo;
      }
    }
  }
}

// ---------------- K2: Wh = x @ W  (fp32, 64x64 tile, k=128) -----------------
__global__ __launch_bounds__(256) void k_wh(
    const float* __restrict__ x, const float* __restrict__ Wm, float* __restrict__ Wh) {
  __shared__ float xs[64 * 65];
  __shared__ float wss[128 * 64];
  const int bh = blockIdx.y, b = bh >> 3, h = bh & 7;
  const int i0 = blockIdx.x * 64;
  const int t = threadIdx.x;
  const float* xp = x + ((long long)b * 2048 + i0) * 128;
  const float* wp = Wm + (long long)h * (128 * 64);
  #pragma unroll
  for (int f = 0; f < 8; ++f)
    ((float4*)wss)[f * 256 + t] = ((const float4*)wp)[f * 256 + t];
  const int tx = t & 15, ty = t >> 4;
  float acc[4][4] = {};
  for (int kc = 0; kc < 2; ++kc) {
    __syncthreads();
    #pragma unroll
    for (int f = 0; f < 4; ++f) {
      int ff = f * 256 + t;
      int i = ff >> 4, kq = ff & 15;
      float4 v = *(const float4*)(xp + (long long)i * 128 + kc * 64 + kq * 4);
      int base = i * 65 + kq * 4;
      xs[base] = v.x; xs[base + 1] = v.y; xs[base + 2] = v.z; xs[base + 3] = v.w;
    }
    __syncthreads();
    for (int k = 0; k < 64; ++k) {
      float4 wv = *(const float4*)&wss[(kc * 64 + k) * 64 + tx * 4];
      float xv0 = xs[(ty * 4 + 0) * 65 + k];
      float xv1 = xs[(ty * 4 + 1) * 65 + k];
      float xv2 = xs[(ty * 4 + 2) * 65 + k];
      float xv3 = xs[(ty * 4 + 3) * 65 + k];
      acc[0][0] += xv0 * wv.x; acc[0][1] += xv0 * wv.y; acc[0][2] += xv0 * wv.z; acc[0][3] += xv0 * wv.w;
      acc[1][0] += xv1 * wv.x; acc[1][1] += xv1 * wv.y; acc[1][2] += xv1 * wv.z; acc[1][3] += xv1 * wv.w;
      acc[2][0] += xv2 * wv.x; acc[2][1] += xv2 * wv.y; acc[2][2] += xv2 * wv.z; acc[2][3] += xv2 * wv.w;
      acc[3][0] += xv3 * wv.x; acc[3][1] += xv3 * wv.y; acc[3][2] += xv3 * wv.z; acc[3][3] += xv3 * wv.w;
    }
  }
  float* op = Wh + (((long long)bh * 2048) + i0 + ty * 4) * 64 + tx * 4;
  #pragma unroll
  for (int ii = 0; ii < 4; ++ii) {
    float4 v = make_float4(acc[ii][0], acc[ii][1], acc[ii][2], acc[ii][3]);
    *(float4*)(op + (long long)ii * 64) = v;
  }
}

// ------- K2b/K5b: fp32 [G][2048][D] -> bf16 MFMA B-fragment order -----------
// dst element order: [g][jc(32)][ks(2)][nt(D/16)][lane(64)][jj(8)]
// where B[k=(lane>>4)*8+jj][n=lane&15] = src[jc*64+ks*32+(lane>>4)*8+jj][nt*16+(lane&15)]
template <int D>
__global__ __launch_bounds__(256) void k_repack(
    const float* __restrict__ src, short* __restrict__ dst) {
  const long long T = (long long)blockIdx.x * 256 + threadIdx.x;
  const int lane = (int)(T & 63);
  long long r = T >> 6;
  constexpr int NT = D / 16;
  const int nt = (int)(r & (NT - 1)); r >>= (NT == 4 ? 2 : 1);
  const int ks = (int)(r & 1); r >>= 1;
  const int jc = (int)(r & 31);
  const long long g = r >> 5;
  const int d = nt * 16 + (lane & 15);
  const long long jb = (long long)jc * 64 + ks * 32 + ((lane >> 4) * 8);
  const float* sp = src + (g * 2048 + jb) * D + d;
  short8 o;
  #pragma unroll
  for (int jj = 0; jj < 8; ++jj) o[jj] = (short)f2bf(sp[(long long)jj * D]);
  *(short8*)(dst + T * 8) = o;
}

// ---------------- K3: f1/f2 = Wh . a1/a2 (one wave per row) -----------------
__global__ __launch_bounds__(256) void k_f12(
    const float* __restrict__ Wh, const float* __restrict__ a1,
    const float* __restrict__ a2, float* __restrict__ f1, float* __restrict__ f2) {
  const long long row = ((long long)blockIdx.x * 256 + threadIdx.x) >> 6;
  const int lane = threadIdx.x & 63;
  const int h = (int)((row >> 11) & 7);
  float v = Wh[row * 64 + lane];
  float p1 = v * a1[h * 64 + lane];
  float p2 = v * a2[h * 64 + lane];
  #pragma unroll
  for (int off = 32; off; off >>= 1) {
    p1 += __shfl_xor(p1, off);
    p2 += __shfl_xor(p2, off);
  }
  if (lane == 0) { f1[row] = p1; f2[row] = p2; }
}

// ---------------- K4: layer-1 attention, MFMA, no LDS/barriers --------------
__global__ __launch_bounds__(256) void k_attn1(
    const short* __restrict__ whf, const float* __restrict__ f1v,
    const float* __restrict__ f2v, const unsigned long long* __restrict__ maskb,
    float* __restrict__ h1) {
  const int bh = blockIdx.y, b = bh >> 3, hh = bh & 7;
  const int t = threadIdx.x;
  const int lane = t & 63, wid = t >> 6;
  const int cl = lane & 15, q = lane >> 4;
  const long long i_g = (long long)blockIdx.x * 64 + wid * 16 + cl;
  const float f1i = f1v[(long long)bh * 2048 + i_g];
  const unsigned long long* mp = maskb + ((long long)b * 2048 + i_g) * 32;
  const float* f2b = f2v + (long long)bh * 2048;
  const short* whfb = whf + (long long)bh * 131072;
  float4_ acc0 = {0.f, 0.f, 0.f, 0.f}, acc1 = acc0, acc2 = acc0, acc3 = acc0;
  float zpart = 0.f;
  for (int jc = 0; jc < 32; ++jc) {
    const unsigned long long mw = mp[jc];
    #pragma unroll
    for (int ks = 0; ks < 2; ++ks) {
      const unsigned mb = (unsigned)(mw >> (ks * 32 + q * 8)) & 0xffu;
      const float* fp = f2b + jc * 64 + ks * 32 + q * 8;
      const float4 fa = *(const float4*)fp;
      const float4 fb = *(const float4*)(fp + 4);
      const float f2j[8] = {fa.x, fa.y, fa.z, fa.w, fb.x, fb.y, fb.z, fb.w};
      short8 af;
      #pragma unroll
      for (int jj = 0; jj < 8; ++jj) {
        float e = f1i + f2j[jj];
        e = fmaxf(e, 0.2f * e);                       // leaky_relu
        float w = ((mb >> jj) & 1u) ? __expf(e) : 0.f;
        unsigned short bw = f2bf(w);
        af[jj] = (short)bw;
        zpart += bf2f(bw);                            // Z consistent with bf16 w
      }
      const short* bb = whfb + (jc * 2 + ks) * 2048 + lane * 8;
      short8 b0 = *(const short8*)(bb);
      short8 b1 = *(const short8*)(bb + 512);
      short8 b2 = *(const short8*)(bb + 1024);
      short8 b3 = *(const short8*)(bb + 1536);
      acc0 = __builtin_amdgcn_mfma_f32_16x16x32_bf16(af, b0, acc0, 0, 0, 0);
      acc1 = __builtin_amdgcn_mfma_f32_16x16x32_bf16(af, b1, acc1, 0, 0, 0);
      acc2 = __builtin_amdgcn_mfma_f32_16x16x32_bf16(af, b2, acc2, 0, 0, 0);
      acc3 = __builtin_amdgcn_mfma_f32_16x16x32_bf16(af, b3, acc3, 0, 0, 0);
    }
  }
  zpart += __shfl_xor(zpart, 16);
  zpart += __shfl_xor(zpart, 32);    // all lanes: Z for row (lane&15)
  float4_ accs[4] = {acc0, acc1, acc2, acc3};
  #pragma unroll
  for (int reg = 0; reg < 4; ++reg) {
    const int ir = q * 4 + reg;                       // C row
    const float zi = __shfl(zpart, ir);
    const float rz = 1.f / zi;
    const long long row = (long long)blockIdx.x * 64 + wid * 16 + ir;
    float* op = h1 + ((long long)b * 2048 + row) * 512 + hh * 64 + cl;
    #pragma unroll
    for (int nt = 0; nt < 4; ++nt) {
      float v = accs[nt][reg] * rz;
      v = (v > 0.f) ? v : (__expf(v) - 1.f);          // elu
      op[nt * 16] = v;
    }
  }
}

// ---------------- K5: Wh2 = h1 @ Wo + g1/g2 epilogue (fp32) -----------------
// 32 rows/block (grid 256), h-slab in 64KB LDS, thread=(c,ty), 4 rows/thread.
// Inner: 4 broadcast ds_read_b128 (2 distinct addr/wave, conflict-free) +
// 4 coalesced Wo dword loads (L1-resident) + 16 FMA. ~40 VGPR, no spill.
__global__ __launch_bounds__(256) void k_ogemm(
    const float* __restrict__ h1, const float* __restrict__ Wo,
    const float* __restrict__ ao1, const float* __restrict__ ao2,
    float* __restrict__ Wh2, float* __restrict__ g1, float* __restrict__ g2) {
  __shared__ float hsm[32 * 512];                      // 64 KB exactly
  const long long r0 = (long long)blockIdx.x * 32;
  const int t = threadIdx.x;
  const int c = t & 31, ty = t >> 5;                   // c: class col, ty: 0..7
  const float4* src = (const float4*)(h1 + r0 * 512);
  float4* dstv = (float4*)hsm;
  #pragma unroll
  for (int j = 0; j < 16; ++j) dstv[j * 256 + t] = src[j * 256 + t];
  __syncthreads();
  float acc0 = 0.f, acc1 = 0.f, acc2 = 0.f, acc3 = 0.f;
  for (int kc = 0; kc < 128; ++kc) {
    const int k = kc * 4;
    const float w0 = Wo[(k + 0) * 32 + c];
    const float w1 = Wo[(k + 1) * 32 + c];
    const float w2 = Wo[(k + 2) * 32 + c];
    const float w3 = Wo[(k + 3) * 32 + c];
    const float4 ha = *(const float4*)&hsm[(ty + 0) * 512 + k];
    const float4 hb = *(const float4*)&hsm[(ty + 8) * 512 + k];
    const float4 hc = *(const float4*)&hsm[(ty + 16) * 512 + k];
    const float4 hd = *(const float4*)&hsm[(ty + 24) * 512 + k];
    acc0 += ha.x * w0 + ha.y * w1 + ha.z * w2 + ha.w * w3;
    acc1 += hb.x * w0 + hb.y * w1 + hb.z * w2 + hb.w * w3;
    acc2 += hc.x * w0 + hc.y * w1 + hc.z * w2 + hc.w * w3;
    acc3 += hd.x * w0 + hd.y * w1 + hd.z * w2 + hd.w * w3;
  }
  const float a1c = ao1[c], a2c = ao2[c];
  const float accs[4] = {acc0, acc1, acc2, acc3};
  #pragma unroll
  for (int m = 0; m < 4; ++m) {
    const long long row = r0 + ty + 8 * m;
    Wh2[row * 32 + c] = accs[m];
    float p1 = accs[m] * a1c, p2 = accs[m] * a2c;
    #pragma unroll
    for (int off = 1; off < 32; off <<= 1) {
      p1 += __shfl_xor(p1, off);
      p2 += __shfl_xor(p2, off);
    }
    if (c == 0) { g1[row] = p1; g2[row] = p2; }
  }
}

// ---------------- K6: output attention, MFMA, 4-way j-split -----------------
__global__ __launch_bounds__(256) void k_attn2(
    const short* __restrict__ whf2, const float* __restrict__ g1v,
    const float* __restrict__ g2v, const unsigned long long* __restrict__ maskb,
    float* __restrict__ outp) {
  __shared__ float accs[4][16][33];
  __shared__ float zsh[64];
  const int b = blockIdx.y;
  const long long i0 = (long long)blockIdx.x * 16;
  const int t = threadIdx.x, lane = t & 63, wid = t >> 6;
  const int cl = lane & 15, q = lane >> 4;
  const float g1i = g1v[(long long)b * 2048 + i0 + cl];
  const unsigned long long* mp = maskb + ((long long)b * 2048 + i0 + cl) * 32;
  const float* g2b = g2v + (long long)b * 2048;
  const short* wb = whf2 + (long long)b * 65536;
  float4_ acc0 = {0.f, 0.f, 0.f, 0.f}, acc1 = acc0;
  float zpart = 0.f;
  for (int c8 = 0; c8 < 8; ++c8) {
    const int jc = wid * 8 + c8;                       // each wave: 512 j's
    const unsigned long long mw = mp[jc];
    #pragma unroll
    for (int ks = 0; ks < 2; ++ks) {
      const unsigned mb = (unsigned)(mw >> (ks * 32 + q * 8)) & 0xffu;
      const float* fp = g2b + jc * 64 + ks * 32 + q * 8;
      const float4 fa = *(const float4*)fp;
      const float4 fb = *(const float4*)(fp + 4);
      const float g2j[8] = {fa.x, fa.y, fa.z, fa.w, fb.x, fb.y, fb.z, fb.w};
      short8 af;
      #pragma unroll
      for (int jj = 0; jj < 8; ++jj) {
        float e = g1i + g2j[jj];
        e = fmaxf(e, 0.2f * e);
        float w = ((mb >> jj) & 1u) ? __expf(e) : 0.f;
        unsigned short bw = f2bf(w);
        af[jj] = (short)bw;
        zpart += bf2f(bw);
      }
      const short* bb = wb + (jc * 2 + ks) * 1024 + lane * 8;
      short8 b0 = *(const short8*)bb;
      short8 b1 = *(const short8*)(bb + 512);
      acc0 = __builtin_amdgcn_mfma_f32_16x16x32_bf16(af, b0, acc0, 0, 0, 0);
      acc1 = __builtin_amdgcn_mfma_f32_16x16x32_bf16(af, b1, acc1, 0, 0, 0);
    }
  }
  zpart += __shfl_xor(zpart, 16);
  zpart += __shfl_xor(zpart, 32);
  if (q == 0) zsh[wid * 16 + cl] = zpart;
  float4_ a01[2] = {acc0, acc1};
  #pragma unroll
  for (int nt = 0; nt < 2; ++nt)
    #pragma unroll
    for (int reg = 0; reg < 4; ++reg)
      accs[wid][q * 4 + reg][nt * 16 + cl] = a01[nt][reg];
  __syncthreads();
  #pragma unroll
  for (int r = 0; r < 2; ++r) {
    int o = r * 256 + t;
    int il = o >> 5, c = o & 31;
    float s = accs[0][il][c] + accs[1][il][c] + accs[2][il][c] + accs[3][il][c];
    float Z = zsh[il] + zsh[16 + il] + zsh[32 + il] + zsh[48 + il];
    outp[((long long)b * 2048 + i0 + il) * 32 + c] = s / Z;
  }
}

// ---------------------------------------------------------------------------
extern "C" void kernel_launch(void* const* d_in, const int* in_sizes, int n_in,
                              void* d_out, int out_size, void* d_ws, size_t ws_size,
                              hipStream_t stream) {
  const float* x   = (const float*)d_in[0];
  const int*   adj = (const int*)d_in[1];
  const float* W   = (const float*)d_in[2];
  const float* a1  = (const float*)d_in[3];
  const float* a2  = (const float*)d_in[4];
  const float* Wo  = (const float*)d_in[5];
  const float* ao1 = (const float*)d_in[6];
  const float* ao2 = (const float*)d_in[7];
  float* out = (float*)d_out;
  char* ws = (char*)d_ws;

  unsigned long long* maskb = (unsigned long long*)(ws + 0);          //  2 MB
  float* Wh   = (float*)(ws + 2097152);                               // 16 MB
  short* WhF  = (short*)(ws + 18874368);                              //  8 MB bf16 frags
  float* f1   = (float*)(ws + 27262976);
  float* f2   = (float*)(ws + 27525120);
  float* h1   = (float*)(ws + 27787264);                              // 16 MB
  float* Wh2  = (float*)(ws + 44564480);                              //  1 MB
  short* Wh2F = (short*)(ws + 45613056);                              //  0.5 MB
  float* g1   = (float*)(ws + 46137344);
  float* g2   = (float*)(ws + 46170112);

  hipLaunchKernelGGL(k_pack_mask, dim3(2048), dim3(256), 0, stream, adj, maskb);
  hipLaunchKernelGGL(k_wh, dim3(32, 32), dim3(256), 0, stream, x, W, Wh);
  hipLaunchKernelGGL((k_repack<64>), dim3(2048), dim3(256), 0, stream, Wh, WhF);
  hipLaunchKernelGGL(k_f12, dim3(16384), dim3(256), 0, stream, Wh, a1, a2, f1, f2);
  hipLaunchKernelGGL(k_attn1, dim3(32, 32), dim3(256), 0, stream, WhF, f1, f2, maskb, h1);
  hipLaunchKernelGGL(k_ogemm, dim3(256), dim3(256), 0, stream, h1, Wo, ao1, ao2, Wh2, g1, g2);
  hipLaunchKernelGGL((k_repack<32>), dim3(128), dim3(256), 0, stream, Wh2, Wh2F);
  hipLaunchKernelGGL(k_attn2, dim3(128, 4), dim3(256), 0, stream, Wh2F, g1, g2, maskb, out);
}

// Round 3
// 235.967 us; speedup vs baseline: 2.3957x; 1.0107x over previous
//
#include <hip/hip_runtime.h>

// GAT forward, MI355X. Sizes fixed by the reference:
// B=4, N=2048, NFEAT=128, NHID=64, NCLASS=32, NHEADS=8, alpha=0.2
//
// Pipeline:
//  K1 pack_mask : adj(268MB i32) -> 2MB bitmask        (HBM-bound, ~43us floor)
//  K2 wh        : Wh[b,h] = x[b] @ W[h]  (fp32 tile GEMM)
//  K2b repack<64>: Wh -> bf16 MFMA-B-fragment order
//  K3 f12       : f1/f2 = Wh . a1/a2 (wave reduce), PRESCALED by log2(e)
//  K4 attn1     : MFMA flash-style: weights generated per-lane directly in
//                 A-frag layout; Z via 5th MFMA with ones-B; bf16 pack via
//                 +0x8000 + v_perm. No LDS, no barriers.
//  K5 ogemm     : Wh2 = h1 @ Wo (fp32, LDS slab) + g1/g2 epilogue (prescaled)
//  K5b repack<32>: Wh2 -> bf16 frag order
//  K6 attn2     : same MFMA trick, j-split across 4 waves + LDS combine
//
// Softmax max-subtraction skipped (scores ~N(0,1.3^2); exp2 safe in fp32 by
// huge margin; softmax is shift-invariant). Z accumulated by MFMA from the
// same bf16-rounded weights as the numerator -> consistent ratio.

typedef short  short8  __attribute__((ext_vector_type(8)));
typedef float  float4_ __attribute__((ext_vector_type(4)));
typedef unsigned int uint4_ __attribute__((ext_vector_type(4)));

#if __has_builtin(__builtin_amdgcn_exp2f)
#define EXP2(x) __builtin_amdgcn_exp2f(x)
#else
#define EXP2(x) __expf((x) * 0.69314718055994531f)
#endif
#define LOG2E 1.44269504088896340f

static __device__ __forceinline__ unsigned short f2bf(float f) {
  unsigned u = __float_as_uint(f);
  u += 0x7fffu + ((u >> 16) & 1u);          // RNE
  return (unsigned short)(u >> 16);
}

// weight pipeline: t (prescaled by log2e) -> masked leakyrelu -> exp2 ->
// fp32 bits + 0x8000 (half-up round to bf16 in high 16)
static __device__ __forceinline__ unsigned wgen(float t, unsigned mb, unsigned bit) {
  float l = fmaxf(t, 0.2f * t);
  l = (mb & bit) ? l : -1000.f;             // exp2(-1000) == 0
  return __float_as_uint(EXP2(l)) + 0x8000u;
}

// ---------------- K1: adj -> bitmask (word w bit l <=> column w*64+l) -------
__global__ __launch_bounds__(256) void k_pack_mask(
    const int* __restrict__ adj, unsigned long long* __restrict__ maskb) {
  const int t = threadIdx.x;
  const int lane = t & 63, wid = t >> 6;
  const int s = lane & 15;
  const long long row0 = (long long)blockIdx.x * 4;
  for (int rr = 0; rr < 4; ++rr) {
    const long long row = row0 + rr;
    const int4* src = (const int4*)(adj + row * 2048);
    #pragma unroll
    for (int c = 0; c < 2; ++c) {
      int4 v = src[c * 256 + t];
      unsigned nib = (v.x != 0 ? 1u : 0u) | (v.y != 0 ? 2u : 0u) |
                     (v.z != 0 ? 4u : 0u) | (v.w != 0 ? 8u : 0u);
      unsigned lo = (s < 8) ? (nib << (s * 4)) : 0u;
      unsigned hi = (s >= 8) ? (nib << ((s - 8) * 4)) : 0u;
      #pragma unroll
      for (int off = 1; off < 16; off <<= 1) {
        lo |= __shfl_xor(lo, off);
        hi |= __shfl_xor(hi, off);
      }
      if (s == 0) {
        int word = c * 16 + wid * 4 + (lane >> 4);
        maskb[row * 32 + word] = ((unsigned long long)hi << 32) | (unsigned long long)lo;
      }
    }
  }
}

// ---------------- K2: Wh = x @ W  (fp32, 64x64 tile, k=128) -----------------
__global__ __launch_bounds__(256) void k_wh(
    const float* __restrict__ x, const float* __restrict__ Wm, float* __restrict__ Wh) {
  __shared__ float xs[64 * 65];
  __shared__ float wss[128 * 64];
  const int bh = blockIdx.y, b = bh >> 3, h = bh & 7;
  const int i0 = blockIdx.x * 64;
  const int t = threadIdx.x;
  const float* xp = x + ((long long)b * 2048 + i0) * 128;
  const float* wp = Wm + (long long)h * (128 * 64);
  #pragma unroll
  for (int f = 0; f < 8; ++f)
    ((float4*)wss)[f * 256 + t] = ((const float4*)wp)[f * 256 + t];
  const int tx = t & 15, ty = t >> 4;
  float acc[4][4] = {};
  for (int kc = 0; kc < 2; ++kc) {
    __syncthreads();
    #pragma unroll
    for (int f = 0; f < 4; ++f) {
      int ff = f * 256 + t;
      int i = ff >> 4, kq = ff & 15;
      float4 v = *(const float4*)(xp + (long long)i * 128 + kc * 64 + kq * 4);
      int base = i * 65 + kq * 4;
      xs[base] = v.x; xs[base + 1] = v.y; xs[base + 2] = v.z; xs[base + 3] = v.w;
    }
    __syncthreads();
    for (int k = 0; k < 64; ++k) {
      float4 wv = *(const float4*)&wss[(kc * 64 + k) * 64 + tx * 4];
      float xv0 = xs[(ty * 4 + 0) * 65 + k];
      float xv1 = xs[(ty * 4 + 1) * 65 + k];
      float xv2 = xs[(ty * 4 + 2) * 65 + k];
      float xv3 = xs[(ty * 4 + 3) * 65 + k];
      acc[0][0] += xv0 * wv.x; acc[0][1] += xv0 * wv.y; acc[0][2] += xv0 * wv.z; acc[0][3] += xv0 * wv.w;
      acc[1][0] += xv1 * wv.x; acc[1][1] += xv1 * wv.y; acc[1][2] += xv1 * wv.z; acc[1][3] += xv1 * wv.w;
      acc[2][0] += xv2 * wv.x; acc[2][1] += xv2 * wv.y; acc[2][2] += xv2 * wv.z; acc[2][3] += xv2 * wv.w;
      acc[3][0] += xv3 * wv.x; acc[3][1] += xv3 * wv.y; acc[3][2] += xv3 * wv.z; acc[3][3] += xv3 * wv.w;
    }
  }
  float* op = Wh + (((long long)bh * 2048) + i0 + ty * 4) * 64 + tx * 4;
  #pragma unroll
  for (int ii = 0; ii < 4; ++ii) {
    float4 v = make_float4(acc[ii][0], acc[ii][1], acc[ii][2], acc[ii][3]);
    *(float4*)(op + (long long)ii * 64) = v;
  }
}

// ------- K2b/K5b: fp32 [G][2048][D] -> bf16 MFMA B-fragment order -----------
// dst element order: [g][jc(32)][ks(2)][nt(D/16)][lane(64)][jj(8)]
// where B[k=(lane>>4)*8+jj][n=lane&15] = src[jc*64+ks*32+(lane>>4)*8+jj][nt*16+(lane&15)]
template <int D>
__global__ __launch_bounds__(256) void k_repack(
    const float* __restrict__ src, short* __restrict__ dst) {
  const long long T = (long long)blockIdx.x * 256 + threadIdx.x;
  const int lane = (int)(T & 63);
  long long r = T >> 6;
  constexpr int NT = D / 16;
  const int nt = (int)(r & (NT - 1)); r >>= (NT == 4 ? 2 : 1);
  const int ks = (int)(r & 1); r >>= 1;
  const int jc = (int)(r & 31);
  const long long g = r >> 5;
  const int d = nt * 16 + (lane & 15);
  const long long jb = (long long)jc * 64 + ks * 32 + ((lane >> 4) * 8);
  const float* sp = src + (g * 2048 + jb) * D + d;
  short8 o;
  #pragma unroll
  for (int jj = 0; jj < 8; ++jj) o[jj] = (short)f2bf(sp[(long long)jj * D]);
  *(short8*)(dst + T * 8) = o;
}

// ---------------- K3: f1/f2 = log2e * (Wh . a1/a2) --------------------------
__global__ __launch_bounds__(256) void k_f12(
    const float* __restrict__ Wh, const float* __restrict__ a1,
    const float* __restrict__ a2, float* __restrict__ f1, float* __restrict__ f2) {
  const long long row = ((long long)blockIdx.x * 256 + threadIdx.x) >> 6;
  const int lane = threadIdx.x & 63;
  const int h = (int)((row >> 11) & 7);
  float v = Wh[row * 64 + lane];
  float p1 = v * a1[h * 64 + lane];
  float p2 = v * a2[h * 64 + lane];
  #pragma unroll
  for (int off = 32; off; off >>= 1) {
    p1 += __shfl_xor(p1, off);
    p2 += __shfl_xor(p2, off);
  }
  if (lane == 0) { f1[row] = p1 * LOG2E; f2[row] = p2 * LOG2E; }
}

// ---------------- K4: layer-1 attention, MFMA, no LDS/barriers --------------
__global__ __launch_bounds__(256) void k_attn1(
    const short* __restrict__ whf, const float* __restrict__ f1v,
    const float* __restrict__ f2v, const unsigned long long* __restrict__ maskb,
    float* __restrict__ h1) {
  const int bh = blockIdx.y, b = bh >> 3, hh = bh & 7;
  const int t = threadIdx.x;
  const int lane = t & 63, wid = t >> 6;
  const int cl = lane & 15, q = lane >> 4;
  const long long i_g = (long long)blockIdx.x * 64 + wid * 16 + cl;
  const float f1i = f1v[(long long)bh * 2048 + i_g];
  const uint2* mpp = (const uint2*)(maskb + ((long long)b * 2048 + i_g) * 32);
  const float* f2b = f2v + (long long)bh * 2048;
  const short* whfb = whf + (long long)bh * 131072;
  const short8 vones = {16256, 16256, 16256, 16256, 16256, 16256, 16256, 16256};
  float4_ acc0 = {0.f, 0.f, 0.f, 0.f}, acc1 = acc0, acc2 = acc0, acc3 = acc0;
  float4_ accz = acc0;
  const int qs = q * 8;
  for (int jc = 0; jc < 32; ++jc) {
    const uint2 mw = mpp[jc];
    #pragma unroll
    for (int ks = 0; ks < 2; ++ks) {
      const unsigned mb = (ks ? mw.y : mw.x) >> qs;   // target byte in bits 0..7
      const float* fp = f2b + jc * 64 + ks * 32 + qs;
      const float4 fa = *(const float4*)fp;
      const float4 fb = *(const float4*)(fp + 4);
      unsigned u0 = wgen(f1i + fa.x, mb, 1u);
      unsigned u1 = wgen(f1i + fa.y, mb, 2u);
      unsigned u2 = wgen(f1i + fa.z, mb, 4u);
      unsigned u3 = wgen(f1i + fa.w, mb, 8u);
      unsigned u4 = wgen(f1i + fb.x, mb, 16u);
      unsigned u5 = wgen(f1i + fb.y, mb, 32u);
      unsigned u6 = wgen(f1i + fb.z, mb, 64u);
      unsigned u7 = wgen(f1i + fb.w, mb, 128u);
      uint4_ pk;
      pk.x = __builtin_amdgcn_perm(u1, u0, 0x07060302u);
      pk.y = __builtin_amdgcn_perm(u3, u2, 0x07060302u);
      pk.z = __builtin_amdgcn_perm(u5, u4, 0x07060302u);
      pk.w = __builtin_amdgcn_perm(u7, u6, 0x07060302u);
      const short8 af = __builtin_bit_cast(short8, pk);
      const short* bb = whfb + (jc * 2 + ks) * 2048 + lane * 8;
      short8 b0 = *(const short8*)(bb);
      short8 b1 = *(const short8*)(bb + 512);
      short8 b2 = *(const short8*)(bb + 1024);
      short8 b3 = *(const short8*)(bb + 1536);
      acc0 = __builtin_amdgcn_mfma_f32_16x16x32_bf16(af, b0, acc0, 0, 0, 0);
      acc1 = __builtin_amdgcn_mfma_f32_16x16x32_bf16(af, b1, acc1, 0, 0, 0);
      acc2 = __builtin_amdgcn_mfma_f32_16x16x32_bf16(af, b2, acc2, 0, 0, 0);
      acc3 = __builtin_amdgcn_mfma_f32_16x16x32_bf16(af, b3, acc3, 0, 0, 0);
      accz = __builtin_amdgcn_mfma_f32_16x16x32_bf16(af, vones, accz, 0, 0, 0);
    }
  }
  float4_ accs[4] = {acc0, acc1, acc2, acc3};
  #pragma unroll
  for (int reg = 0; reg < 4; ++reg) {
    const int ir = q * 4 + reg;                       // C row
    const float rz = 1.f / accz[reg];                 // Z for row ir (any col)
    const long long row = (long long)blockIdx.x * 64 + wid * 16 + ir;
    float* op = h1 + ((long long)b * 2048 + row) * 512 + hh * 64 + cl;
    #pragma unroll
    for (int nt = 0; nt < 4; ++nt) {
      float v = accs[nt][reg] * rz;
      v = (v > 0.f) ? v : (__expf(v) - 1.f);          // elu
      op[nt * 16] = v;
    }
  }
}

// ---------------- K5: Wh2 = h1 @ Wo + g1/g2 epilogue (fp32) -----------------
// 32 rows/block (grid 256), h-slab in 64KB LDS, thread=(c,ty), 4 rows/thread.
__global__ __launch_bounds__(256) void k_ogemm(
    const float* __restrict__ h1, const float* __restrict__ Wo,
    const float* __restrict__ ao1, const float* __restrict__ ao2,
    float* __restrict__ Wh2, float* __restrict__ g1, float* __restrict__ g2) {
  __shared__ float hsm[32 * 512];                      // 64 KB exactly
  const long long r0 = (long long)blockIdx.x * 32;
  const int t = threadIdx.x;
  const int c = t & 31, ty = t >> 5;                   // c: class col, ty: 0..7
  const float4* src = (const float4*)(h1 + r0 * 512);
  float4* dstv = (float4*)hsm;
  #pragma unroll
  for (int j = 0; j < 16; ++j) dstv[j * 256 + t] = src[j * 256 + t];
  __syncthreads();
  float acc0 = 0.f, acc1 = 0.f, acc2 = 0.f, acc3 = 0.f;
  for (int kc = 0; kc < 128; ++kc) {
    const int k = kc * 4;
    const float w0 = Wo[(k + 0) * 32 + c];
    const float w1 = Wo[(k + 1) * 32 + c];
    const float w2 = Wo[(k + 2) * 32 + c];
    const float w3 = Wo[(k + 3) * 32 + c];
    const float4 ha = *(const float4*)&hsm[(ty + 0) * 512 + k];
    const float4 hb = *(const float4*)&hsm[(ty + 8) * 512 + k];
    const float4 hc = *(const float4*)&hsm[(ty + 16) * 512 + k];
    const float4 hd = *(const float4*)&hsm[(ty + 24) * 512 + k];
    acc0 += ha.x * w0 + ha.y * w1 + ha.z * w2 + ha.w * w3;
    acc1 += hb.x * w0 + hb.y * w1 + hb.z * w2 + hb.w * w3;
    acc2 += hc.x * w0 + hc.y * w1 + hc.z * w2 + hc.w * w3;
    acc3 += hd.x * w0 + hd.y * w1 + hd.z * w2 + hd.w * w3;
  }
  const float a1c = ao1[c], a2c = ao2[c];
  const float accs[4] = {acc0, acc1, acc2, acc3};
  #pragma unroll
  for (int m = 0; m < 4; ++m) {
    const long long row = r0 + ty + 8 * m;
    Wh2[row * 32 + c] = accs[m];
    float p1 = accs[m] * a1c, p2 = accs[m] * a2c;
    #pragma unroll
    for (int off = 1; off < 32; off <<= 1) {
      p1 += __shfl_xor(p1, off);
      p2 += __shfl_xor(p2, off);
    }
    if (c == 0) { g1[row] = p1 * LOG2E; g2[row] = p2 * LOG2E; }
  }
}

// ---------------- K6: output attention, MFMA, 4-way j-split -----------------
__global__ __launch_bounds__(256) void k_attn2(
    const short* __restrict__ whf2, const float* __restrict__ g1v,
    const float* __restrict__ g2v, const unsigned long long* __restrict__ maskb,
    float* __restrict__ outp) {
  __shared__ float accs[4][16][33];
  __shared__ float zsh[64];
  const int b = blockIdx.y;
  const long long i0 = (long long)blockIdx.x * 16;
  const int t = threadIdx.x, lane = t & 63, wid = t >> 6;
  const int cl = lane & 15, q = lane >> 4;
  const float g1i = g1v[(long long)b * 2048 + i0 + cl];
  const uint2* mpp = (const uint2*)(maskb + ((long long)b * 2048 + i0 + cl) * 32);
  const float* g2b = g2v + (long long)b * 2048;
  const short* wb = whf2 + (long long)b * 65536;
  const short8 vones = {16256, 16256, 16256, 16256, 16256, 16256, 16256, 16256};
  float4_ acc0 = {0.f, 0.f, 0.f, 0.f}, acc1 = acc0, accz = acc0;
  const int qs = q * 8;
  for (int c8 = 0; c8 < 8; ++c8) {
    const int jc = wid * 8 + c8;                       // each wave: 512 j's
    const uint2 mw = mpp[jc];
    #pragma unroll
    for (int ks = 0; ks < 2; ++ks) {
      const unsigned mb = (ks ? mw.y : mw.x) >> qs;
      const float* fp = g2b + jc * 64 + ks * 32 + qs;
      const float4 fa = *(const float4*)fp;
      const float4 fb = *(const float4*)(fp + 4);
      unsigned u0 = wgen(g1i + fa.x, mb, 1u);
      unsigned u1 = wgen(g1i + fa.y, mb, 2u);
      unsigned u2 = wgen(g1i + fa.z, mb, 4u);
      unsigned u3 = wgen(g1i + fa.w, mb, 8u);
      unsigned u4 = wgen(g1i + fb.x, mb, 16u);
      unsigned u5 = wgen(g1i + fb.y, mb, 32u);
      unsigned u6 = wgen(g1i + fb.z, mb, 64u);
      unsigned u7 = wgen(g1i + fb.w, mb, 128u);
      uint4_ pk;
      pk.x = __builtin_amdgcn_perm(u1, u0, 0x07060302u);
      pk.y = __builtin_amdgcn_perm(u3, u2, 0x07060302u);
      pk.z = __builtin_amdgcn_perm(u5, u4, 0x07060302u);
      pk.w = __builtin_amdgcn_perm(u7, u6, 0x07060302u);
      const short8 af = __builtin_bit_cast(short8, pk);
      const short* bb = wb + (jc * 2 + ks) * 1024 + lane * 8;
      short8 b0 = *(const short8*)bb;
      short8 b1 = *(const short8*)(bb + 512);
      acc0 = __builtin_amdgcn_mfma_f32_16x16x32_bf16(af, b0, acc0, 0, 0, 0);
      acc1 = __builtin_amdgcn_mfma_f32_16x16x32_bf16(af, b1, acc1, 0, 0, 0);
      accz = __builtin_amdgcn_mfma_f32_16x16x32_bf16(af, vones, accz, 0, 0, 0);
    }
  }
  if (cl == 0) {
    #pragma unroll
    for (int reg = 0; reg < 4; ++reg) zsh[wid * 16 + q * 4 + reg] = accz[reg];
  }
  float4_ a01[2] = {acc0, acc1};
  #pragma unroll
  for (int nt = 0; nt < 2; ++nt)
    #pragma unroll
    for (int reg = 0; reg < 4; ++reg)
      accs[wid][q * 4 + reg][nt * 16 + cl] = a01[nt][reg];
  __syncthreads();
  #pragma unroll
  for (int r = 0; r < 2; ++r) {
    int o = r * 256 + t;
    int il = o >> 5, c = o & 31;
    float s = accs[0][il][c] + accs[1][il][c] + accs[2][il][c] + accs[3][il][c];
    float Z = zsh[il] + zsh[16 + il] + zsh[32 + il] + zsh[48 + il];
    outp[((long long)b * 2048 + i0 + il) * 32 + c] = s / Z;
  }
}

// ---------------------------------------------------------------------------
extern "C" void kernel_launch(void* const* d_in, const int* in_sizes, int n_in,
                              void* d_out, int out_size, void* d_ws, size_t ws_size,
                              hipStream_t stream) {
  const float* x   = (const float*)d_in[0];
  const int*   adj = (const int*)d_in[1];
  const float* W   = (const float*)d_in[2];
  const float* a1  = (const float*)d_in[3];
  const float* a2  = (const float*)d_in[4];
  const float* Wo  = (const float*)d_in[5];
  const float* ao1 = (const float*)d_in[6];
  const float* ao2 = (const float*)d_in[7];
  float* out = (float*)d_out;
  char* ws = (char*)d_ws;

  unsigned long long* maskb = (unsigned long long*)(ws + 0);          //  2 MB
  float* Wh   = (float*)(ws + 2097152);                               // 16 MB
  short* WhF  = (short*)(ws + 18874368);                              //  8 MB bf16 frags
  float* f1   = (float*)(ws + 27262976);
  float* f2   = (float*)(ws + 27525120);
  float* h1   = (float*)(ws + 27787264);                              // 16 MB
  float* Wh2  = (float*)(ws + 44564480);                              //  1 MB
  short* Wh2F = (short*)(ws + 45613056);                              //  0.5 MB
  float* g1   = (float*)(ws + 46137344);
  float* g2   = (float*)(ws + 46170112);

  hipLaunchKernelGGL(k_pack_mask, dim3(2048), dim3(256), 0, stream, adj, maskb);
  hipLaunchKernelGGL(k_wh, dim3(32, 32), dim3(256), 0, stream, x, W, Wh);
  hipLaunchKernelGGL((k_repack<64>), dim3(2048), dim3(256), 0, stream, Wh, WhF);
  hipLaunchKernelGGL(k_f12, dim3(16384), dim3(256), 0, stream, Wh, a1, a2, f1, f2);
  hipLaunchKernelGGL(k_attn1, dim3(32, 32), dim3(256), 0, stream, WhF, f1, f2, maskb, h1);
  hipLaunchKernelGGL(k_ogemm, dim3(256), dim3(256), 0, stream, h1, Wo, ao1, ao2, Wh2, g1, g2);
  hipLaunchKernelGGL((k_repack<32>), dim3(128), dim3(256), 0, stream, Wh2, Wh2F);
  hipLaunchKernelGGL(k_attn2, dim3(128, 4), dim3(256), 0, stream, Wh2F, g1, g2, maskb, out);
}

// Round 4
// 231.377 us; speedup vs baseline: 2.4432x; 1.0198x over previous
//
#include <hip/hip_runtime.h>

// GAT forward, MI355X. Sizes fixed by the reference:
// B=4, N=2048, NFEAT=128, NHID=64, NCLASS=32, NHEADS=8, alpha=0.2
//
// Pipeline:
//  K1 pack_mask : adj(268MB i32) -> 2MB bitmask        (HBM-bound, ~43us floor)
//  K2 wh        : Wh[b,h] = x[b] @ W[h]  (fp32 tile GEMM)
//  K2b repack<64>: Wh -> bf16 MFMA-B-fragment order
//  K3 f12       : f1/f2 = Wh . a1/a2 (wave reduce), PRESCALED by log2(e)
//  K4 attn1     : MFMA flash-style; weights generated per-lane in A-frag
//                 layout; Z via 5th MFMA with ones-B; bf16 pack via
//                 +0x8000 + v_perm. R4: mask+f2 register-prefetched one jc
//                 ahead (chain-head latency was the R3 limiter: VALUBusy
//                 dropped 76->57% with flat time). No LDS, no barriers.
//  K5 ogemm     : Wh2 = h1 @ Wo (fp32, LDS slab) + g1/g2 epilogue (prescaled)
//  K5b repack<32>: Wh2 -> bf16 frag order
//  K6 attn2     : same MFMA trick, j-split across 4 waves + LDS combine
//
// Softmax max-subtraction skipped (scores ~N(0,1.3^2); exp2 safe in fp32 by
// huge margin; softmax is shift-invariant). Z accumulated by MFMA from the
// same bf16-rounded weights as the numerator -> consistent ratio.

typedef short  short8  __attribute__((ext_vector_type(8)));
typedef float  float4_ __attribute__((ext_vector_type(4)));
typedef unsigned int uint4_ __attribute__((ext_vector_type(4)));

#if __has_builtin(__builtin_amdgcn_exp2f)
#define EXP2(x) __builtin_amdgcn_exp2f(x)
#else
#define EXP2(x) __expf((x) * 0.69314718055994531f)
#endif
#define LOG2E 1.44269504088896340f

static __device__ __forceinline__ unsigned short f2bf(float f) {
  unsigned u = __float_as_uint(f);
  u += 0x7fffu + ((u >> 16) & 1u);          // RNE
  return (unsigned short)(u >> 16);
}

// mask bit jj of mb, sign-extended to 0 / 0xFFFFFFFF (1 inst: v_bfe_i32)
static __device__ __forceinline__ unsigned bitm(unsigned mb, int jj) {
#if __has_builtin(__builtin_amdgcn_sbfe)
  return (unsigned)__builtin_amdgcn_sbfe((int)mb, jj, 1);
#else
  return 0u - ((mb >> jj) & 1u);
#endif
}

// weight pipeline: t (prescaled by log2e) -> leakyrelu -> exp2 -> AND with
// mask (masked -> 0x00000000) -> +0x8000 half-up round; perm keeps high16.
// masked: 0x8000 -> bf16 bits 0x0000 == +0.0 after perm.
static __device__ __forceinline__ unsigned wgen(float t, unsigned m) {
  float l = fmaxf(t, 0.2f * t);
  return (__float_as_uint(EXP2(l)) & m) + 0x8000u;
}

// ---------------- K1: adj -> bitmask (word w bit l <=> column w*64+l) -------
__global__ __launch_bounds__(256) void k_pack_mask(
    const int* __restrict__ adj, unsigned long long* __restrict__ maskb) {
  const int t = threadIdx.x;
  const int lane = t & 63, wid = t >> 6;
  const int s = lane & 15;
  const long long row0 = (long long)blockIdx.x * 4;
  for (int rr = 0; rr < 4; ++rr) {
    const long long row = row0 + rr;
    const int4* src = (const int4*)(adj + row * 2048);
    #pragma unroll
    for (int c = 0; c < 2; ++c) {
      int4 v = src[c * 256 + t];
      unsigned nib = (v.x != 0 ? 1u : 0u) | (v.y != 0 ? 2u : 0u) |
                     (v.z != 0 ? 4u : 0u) | (v.w != 0 ? 8u : 0u);
      unsigned lo = (s < 8) ? (nib << (s * 4)) : 0u;
      unsigned hi = (s >= 8) ? (nib << ((s - 8) * 4)) : 0u;
      #pragma unroll
      for (int off = 1; off < 16; off <<= 1) {
        lo |= __shfl_xor(lo, off);
        hi |= __shfl_xor(hi, off);
      }
      if (s == 0) {
        int word = c * 16 + wid * 4 + (lane >> 4);
        maskb[row * 32 + word] = ((unsigned long long)hi << 32) | (unsigned long long)lo;
      }
    }
  }
}

// ---------------- K2: Wh = x @ W  (fp32, 64x64 tile, k=128) -----------------
__global__ __launch_bounds__(256) void k_wh(
    const float* __restrict__ x, const float* __restrict__ Wm, float* __restrict__ Wh) {
  __shared__ float xs[64 * 65];
  __shared__ float wss[128 * 64];
  const int bh = blockIdx.y, b = bh >> 3, h = bh & 7;
  const int i0 = blockIdx.x * 64;
  const int t = threadIdx.x;
  const float* xp = x + ((long long)b * 2048 + i0) * 128;
  const float* wp = Wm + (long long)h * (128 * 64);
  #pragma unroll
  for (int f = 0; f < 8; ++f)
    ((float4*)wss)[f * 256 + t] = ((const float4*)wp)[f * 256 + t];
  const int tx = t & 15, ty = t >> 4;
  float acc[4][4] = {};
  for (int kc = 0; kc < 2; ++kc) {
    __syncthreads();
    #pragma unroll
    for (int f = 0; f < 4; ++f) {
      int ff = f * 256 + t;
      int i = ff >> 4, kq = ff & 15;
      float4 v = *(const float4*)(xp + (long long)i * 128 + kc * 64 + kq * 4);
      int base = i * 65 + kq * 4;
      xs[base] = v.x; xs[base + 1] = v.y; xs[base + 2] = v.z; xs[base + 3] = v.w;
    }
    __syncthreads();
    for (int k = 0; k < 64; ++k) {
      float4 wv = *(const float4*)&wss[(kc * 64 + k) * 64 + tx * 4];
      float xv0 = xs[(ty * 4 + 0) * 65 + k];
      float xv1 = xs[(ty * 4 + 1) * 65 + k];
      float xv2 = xs[(ty * 4 + 2) * 65 + k];
      float xv3 = xs[(ty * 4 + 3) * 65 + k];
      acc[0][0] += xv0 * wv.x; acc[0][1] += xv0 * wv.y; acc[0][2] += xv0 * wv.z; acc[0][3] += xv0 * wv.w;
      acc[1][0] += xv1 * wv.x; acc[1][1] += xv1 * wv.y; acc[1][2] += xv1 * wv.z; acc[1][3] += xv1 * wv.w;
      acc[2][0] += xv2 * wv.x; acc[2][1] += xv2 * wv.y; acc[2][2] += xv2 * wv.z; acc[2][3] += xv2 * wv.w;
      acc[3][0] += xv3 * wv.x; acc[3][1] += xv3 * wv.y; acc[3][2] += xv3 * wv.z; acc[3][3] += xv3 * wv.w;
    }
  }
  float* op = Wh + (((long long)bh * 2048) + i0 + ty * 4) * 64 + tx * 4;
  #pragma unroll
  for (int ii = 0; ii < 4; ++ii) {
    float4 v = make_float4(acc[ii][0], acc[ii][1], acc[ii][2], acc[ii][3]);
    *(float4*)(op + (long long)ii * 64) = v;
  }
}

// ------- K2b/K5b: fp32 [G][2048][D] -> bf16 MFMA B-fragment order -----------
// dst element order: [g][jc(32)][ks(2)][nt(D/16)][lane(64)][jj(8)]
// where B[k=(lane>>4)*8+jj][n=lane&15] = src[jc*64+ks*32+(lane>>4)*8+jj][nt*16+(lane&15)]
template <int D>
__global__ __launch_bounds__(256) void k_repack(
    const float* __restrict__ src, short* __restrict__ dst) {
  const long long T = (long long)blockIdx.x * 256 + threadIdx.x;
  const int lane = (int)(T & 63);
  long long r = T >> 6;
  constexpr int NT = D / 16;
  const int nt = (int)(r & (NT - 1)); r >>= (NT == 4 ? 2 : 1);
  const int ks = (int)(r & 1); r >>= 1;
  const int jc = (int)(r & 31);
  const long long g = r >> 5;
  const int d = nt * 16 + (lane & 15);
  const long long jb = (long long)jc * 64 + ks * 32 + ((lane >> 4) * 8);
  const float* sp = src + (g * 2048 + jb) * D + d;
  short8 o;
  #pragma unroll
  for (int jj = 0; jj < 8; ++jj) o[jj] = (short)f2bf(sp[(long long)jj * D]);
  *(short8*)(dst + T * 8) = o;
}

// ---------------- K3: f1/f2 = log2e * (Wh . a1/a2) --------------------------
__global__ __launch_bounds__(256) void k_f12(
    const float* __restrict__ Wh, const float* __restrict__ a1,
    const float* __restrict__ a2, float* __restrict__ f1, float* __restrict__ f2) {
  const long long row = ((long long)blockIdx.x * 256 + threadIdx.x) >> 6;
  const int lane = threadIdx.x & 63;
  const int h = (int)((row >> 11) & 7);
  float v = Wh[row * 64 + lane];
  float p1 = v * a1[h * 64 + lane];
  float p2 = v * a2[h * 64 + lane];
  #pragma unroll
  for (int off = 32; off; off >>= 1) {
    p1 += __shfl_xor(p1, off);
    p2 += __shfl_xor(p2, off);
  }
  if (lane == 0) { f1[row] = p1 * LOG2E; f2[row] = p2 * LOG2E; }
}

// ---------------- K4: layer-1 attention, MFMA, no LDS/barriers --------------
__global__ __launch_bounds__(256) void k_attn1(
    const short* __restrict__ whf, const float* __restrict__ f1v,
    const float* __restrict__ f2v, const unsigned long long* __restrict__ maskb,
    float* __restrict__ h1) {
  const int bh = blockIdx.y, b = bh >> 3, hh = bh & 7;
  const int t = threadIdx.x;
  const int lane = t & 63, wid = t >> 6;
  const int cl = lane & 15, q = lane >> 4;
  const long long i_g = (long long)blockIdx.x * 64 + wid * 16 + cl;
  const float f1i = f1v[(long long)bh * 2048 + i_g];
  const uint2* mpp = (const uint2*)(maskb + ((long long)b * 2048 + i_g) * 32);
  const float* f2b = f2v + (long long)bh * 2048;
  const short* whfb = whf + (long long)bh * 131072;
  const short8 vones = {16256, 16256, 16256, 16256, 16256, 16256, 16256, 16256};
  float4_ acc0 = {0.f, 0.f, 0.f, 0.f}, acc1 = acc0, acc2 = acc0, acc3 = acc0;
  float4_ accz = acc0;
  const int qs = q * 8;
  // software pipeline: mask + f2 for iter jc in registers, prefetch jc+1.
  // Last-iter prefetch reads 256B past maskb/f2 -> lands in adjacent ws
  // buffers (values unused) — safe, keeps the loop branch-free.
  uint2 mw_c = mpp[0];
  float4 fa0_c = *(const float4*)(f2b + qs);
  float4 fb0_c = *(const float4*)(f2b + qs + 4);
  float4 fa1_c = *(const float4*)(f2b + 32 + qs);
  float4 fb1_c = *(const float4*)(f2b + 36 + qs);
  for (int jc = 0; jc < 32; ++jc) {
    const uint2 mw = mw_c;
    const float4 fa0 = fa0_c, fb0 = fb0_c, fa1 = fa1_c, fb1 = fb1_c;
    {
      const float* fp = f2b + (jc + 1) * 64 + qs;
      mw_c = mpp[jc + 1];
      fa0_c = *(const float4*)fp;
      fb0_c = *(const float4*)(fp + 4);
      fa1_c = *(const float4*)(fp + 32);
      fb1_c = *(const float4*)(fp + 36);
    }
    const short* bb = whfb + (jc * 2) * 2048 + lane * 8;
    {
      const unsigned mb = mw.x >> qs;
      unsigned u0 = wgen(f1i + fa0.x, bitm(mb, 0));
      unsigned u1 = wgen(f1i + fa0.y, bitm(mb, 1));
      unsigned u2 = wgen(f1i + fa0.z, bitm(mb, 2));
      unsigned u3 = wgen(f1i + fa0.w, bitm(mb, 3));
      unsigned u4 = wgen(f1i + fb0.x, bitm(mb, 4));
      unsigned u5 = wgen(f1i + fb0.y, bitm(mb, 5));
      unsigned u6 = wgen(f1i + fb0.z, bitm(mb, 6));
      unsigned u7 = wgen(f1i + fb0.w, bitm(mb, 7));
      uint4_ pk;
      pk.x = __builtin_amdgcn_perm(u1, u0, 0x07060302u);
      pk.y = __builtin_amdgcn_perm(u3, u2, 0x07060302u);
      pk.z = __builtin_amdgcn_perm(u5, u4, 0x07060302u);
      pk.w = __builtin_amdgcn_perm(u7, u6, 0x07060302u);
      const short8 af = __builtin_bit_cast(short8, pk);
      short8 b0 = *(const short8*)(bb);
      short8 b1 = *(const short8*)(bb + 512);
      short8 b2 = *(const short8*)(bb + 1024);
      short8 b3 = *(const short8*)(bb + 1536);
      acc0 = __builtin_amdgcn_mfma_f32_16x16x32_bf16(af, b0, acc0, 0, 0, 0);
      acc1 = __builtin_amdgcn_mfma_f32_16x16x32_bf16(af, b1, acc1, 0, 0, 0);
      acc2 = __builtin_amdgcn_mfma_f32_16x16x32_bf16(af, b2, acc2, 0, 0, 0);
      acc3 = __builtin_amdgcn_mfma_f32_16x16x32_bf16(af, b3, acc3, 0, 0, 0);
      accz = __builtin_amdgcn_mfma_f32_16x16x32_bf16(af, vones, accz, 0, 0, 0);
    }
    {
      const unsigned mb = mw.y >> qs;
      unsigned u0 = wgen(f1i + fa1.x, bitm(mb, 0));
      unsigned u1 = wgen(f1i + fa1.y, bitm(mb, 1));
      unsigned u2 = wgen(f1i + fa1.z, bitm(mb, 2));
      unsigned u3 = wgen(f1i + fa1.w, bitm(mb, 3));
      unsigned u4 = wgen(f1i + fb1.x, bitm(mb, 4));
      unsigned u5 = wgen(f1i + fb1.y, bitm(mb, 5));
      unsigned u6 = wgen(f1i + fb1.z, bitm(mb, 6));
      unsigned u7 = wgen(f1i + fb1.w, bitm(mb, 7));
      uint4_ pk;
      pk.x = __builtin_amdgcn_perm(u1, u0, 0x07060302u);
      pk.y = __builtin_amdgcn_perm(u3, u2, 0x07060302u);
      pk.z = __builtin_amdgcn_perm(u5, u4, 0x07060302u);
      pk.w = __builtin_amdgcn_perm(u7, u6, 0x07060302u);
      const short8 af = __builtin_bit_cast(short8, pk);
      const short* bk = bb + 2048;
      short8 b0 = *(const short8*)(bk);
      short8 b1 = *(const short8*)(bk + 512);
      short8 b2 = *(const short8*)(bk + 1024);
      short8 b3 = *(const short8*)(bk + 1536);
      acc0 = __builtin_amdgcn_mfma_f32_16x16x32_bf16(af, b0, acc0, 0, 0, 0);
      acc1 = __builtin_amdgcn_mfma_f32_16x16x32_bf16(af, b1, acc1, 0, 0, 0);
      acc2 = __builtin_amdgcn_mfma_f32_16x16x32_bf16(af, b2, acc2, 0, 0, 0);
      acc3 = __builtin_amdgcn_mfma_f32_16x16x32_bf16(af, b3, acc3, 0, 0, 0);
      accz = __builtin_amdgcn_mfma_f32_16x16x32_bf16(af, vones, accz, 0, 0, 0);
    }
  }
  float4_ accs[4] = {acc0, acc1, acc2, acc3};
  #pragma unroll
  for (int reg = 0; reg < 4; ++reg) {
    const int ir = q * 4 + reg;                       // C row
    const float rz = 1.f / accz[reg];                 // Z for row ir (any col)
    const long long row = (long long)blockIdx.x * 64 + wid * 16 + ir;
    float* op = h1 + ((long long)b * 2048 + row) * 512 + hh * 64 + cl;
    #pragma unroll
    for (int nt = 0; nt < 4; ++nt) {
      float v = accs[nt][reg] * rz;
      v = (v > 0.f) ? v : (__expf(v) - 1.f);          // elu
      op[nt * 16] = v;
    }
  }
}

// ---------------- K5: Wh2 = h1 @ Wo + g1/g2 epilogue (fp32) -----------------
// 32 rows/block (grid 256), h-slab in 64KB LDS, thread=(c,ty), 4 rows/thread.
__global__ __launch_bounds__(256) void k_ogemm(
    const float* __restrict__ h1, const float* __restrict__ Wo,
    const float* __restrict__ ao1, const float* __restrict__ ao2,
    float* __restrict__ Wh2, float* __restrict__ g1, float* __restrict__ g2) {
  __shared__ float hsm[32 * 512];                      // 64 KB exactly
  const long long r0 = (long long)blockIdx.x * 32;
  const int t = threadIdx.x;
  const int c = t & 31, ty = t >> 5;                   // c: class col, ty: 0..7
  const float4* src = (const float4*)(h1 + r0 * 512);
  float4* dstv = (float4*)hsm;
  #pragma unroll
  for (int j = 0; j < 16; ++j) dstv[j * 256 + t] = src[j * 256 + t];
  __syncthreads();
  float acc0 = 0.f, acc1 = 0.f, acc2 = 0.f, acc3 = 0.f;
  for (int kc = 0; kc < 128; ++kc) {
    const int k = kc * 4;
    const float w0 = Wo[(k + 0) * 32 + c];
    const float w1 = Wo[(k + 1) * 32 + c];
    const float w2 = Wo[(k + 2) * 32 + c];
    const float w3 = Wo[(k + 3) * 32 + c];
    const float4 ha = *(const float4*)&hsm[(ty + 0) * 512 + k];
    const float4 hb = *(const float4*)&hsm[(ty + 8) * 512 + k];
    const float4 hc = *(const float4*)&hsm[(ty + 16) * 512 + k];
    const float4 hd = *(const float4*)&hsm[(ty + 24) * 512 + k];
    acc0 += ha.x * w0 + ha.y * w1 + ha.z * w2 + ha.w * w3;
    acc1 += hb.x * w0 + hb.y * w1 + hb.z * w2 + hb.w * w3;
    acc2 += hc.x * w0 + hc.y * w1 + hc.z * w2 + hc.w * w3;
    acc3 += hd.x * w0 + hd.y * w1 + hd.z * w2 + hd.w * w3;
  }
  const float a1c = ao1[c], a2c = ao2[c];
  const float accs[4] = {acc0, acc1, acc2, acc3};
  #pragma unroll
  for (int m = 0; m < 4; ++m) {
    const long long row = r0 + ty + 8 * m;
    Wh2[row * 32 + c] = accs[m];
    float p1 = accs[m] * a1c, p2 = accs[m] * a2c;
    #pragma unroll
    for (int off = 1; off < 32; off <<= 1) {
      p1 += __shfl_xor(p1, off);
      p2 += __shfl_xor(p2, off);
    }
    if (c == 0) { g1[row] = p1 * LOG2E; g2[row] = p2 * LOG2E; }
  }
}

// ---------------- K6: output attention, MFMA, 4-way j-split -----------------
__global__ __launch_bounds__(256) void k_attn2(
    const short* __restrict__ whf2, const float* __restrict__ g1v,
    const float* __restrict__ g2v, const unsigned long long* __restrict__ maskb,
    float* __restrict__ outp) {
  __shared__ float accs[4][16][33];
  __shared__ float zsh[64];
  const int b = blockIdx.y;
  const long long i0 = (long long)blockIdx.x * 16;
  const int t = threadIdx.x, lane = t & 63, wid = t >> 6;
  const int cl = lane & 15, q = lane >> 4;
  const float g1i = g1v[(long long)b * 2048 + i0 + cl];
  const uint2* mpp = (const uint2*)(maskb + ((long long)b * 2048 + i0 + cl) * 32);
  const float* g2b = g2v + (long long)b * 2048;
  const short* wb = whf2 + (long long)b * 65536;
  const short8 vones = {16256, 16256, 16256, 16256, 16256, 16256, 16256, 16256};
  float4_ acc0 = {0.f, 0.f, 0.f, 0.f}, acc1 = acc0, accz = acc0;
  const int qs = q * 8;
  const int jc0 = wid * 8;
  uint2 mw_c = mpp[jc0];
  float4 fa0_c = *(const float4*)(g2b + jc0 * 64 + qs);
  float4 fb0_c = *(const float4*)(g2b + jc0 * 64 + qs + 4);
  float4 fa1_c = *(const float4*)(g2b + jc0 * 64 + 32 + qs);
  float4 fb1_c = *(const float4*)(g2b + jc0 * 64 + 36 + qs);
  for (int c8 = 0; c8 < 8; ++c8) {
    const int jc = jc0 + c8;                           // each wave: 512 j's
    const uint2 mw = mw_c;
    const float4 fa0 = fa0_c, fb0 = fb0_c, fa1 = fa1_c, fb1 = fb1_c;
    {
      const int jn = jc + ((c8 < 7) ? 1 : 0);          // clamped prefetch
      const float* fp = g2b + jn * 64 + qs;
      mw_c = mpp[jn];
      fa0_c = *(const float4*)fp;
      fb0_c = *(const float4*)(fp + 4);
      fa1_c = *(const float4*)(fp + 32);
      fb1_c = *(const float4*)(fp + 36);
    }
    const short* bb = wb + (jc * 2) * 1024 + lane * 8;
    {
      const unsigned mb = mw.x >> qs;
      unsigned u0 = wgen(g1i + fa0.x, bitm(mb, 0));
      unsigned u1 = wgen(g1i + fa0.y, bitm(mb, 1));
      unsigned u2 = wgen(g1i + fa0.z, bitm(mb, 2));
      unsigned u3 = wgen(g1i + fa0.w, bitm(mb, 3));
      unsigned u4 = wgen(g1i + fb0.x, bitm(mb, 4));
      unsigned u5 = wgen(g1i + fb0.y, bitm(mb, 5));
      unsigned u6 = wgen(g1i + fb0.z, bitm(mb, 6));
      unsigned u7 = wgen(g1i + fb0.w, bitm(mb, 7));
      uint4_ pk;
      pk.x = __builtin_amdgcn_perm(u1, u0, 0x07060302u);
      pk.y = __builtin_amdgcn_perm(u3, u2, 0x07060302u);
      pk.z = __builtin_amdgcn_perm(u5, u4, 0x07060302u);
      pk.w = __builtin_amdgcn_perm(u7, u6, 0x07060302u);
      const short8 af = __builtin_bit_cast(short8, pk);
      short8 b0 = *(const short8*)bb;
      short8 b1 = *(const short8*)(bb + 512);
      acc0 = __builtin_amdgcn_mfma_f32_16x16x32_bf16(af, b0, acc0, 0, 0, 0);
      acc1 = __builtin_amdgcn_mfma_f32_16x16x32_bf16(af, b1, acc1, 0, 0, 0);
      accz = __builtin_amdgcn_mfma_f32_16x16x32_bf16(af, vones, accz, 0, 0, 0);
    }
    {
      const unsigned mb = mw.y >> qs;
      unsigned u0 = wgen(g1i + fa1.x, bitm(mb, 0));
      unsigned u1 = wgen(g1i + fa1.y, bitm(mb, 1));
      unsigned u2 = wgen(g1i + fa1.z, bitm(mb, 2));
      unsigned u3 = wgen(g1i + fa1.w, bitm(mb, 3));
      unsigned u4 = wgen(g1i + fb1.x, bitm(mb, 4));
      unsigned u5 = wgen(g1i + fb1.y, bitm(mb, 5));
      unsigned u6 = wgen(g1i + fb1.z, bitm(mb, 6));
      unsigned u7 = wgen(g1i + fb1.w, bitm(mb, 7));
      uint4_ pk;
      pk.x = __builtin_amdgcn_perm(u1, u0, 0x07060302u);
      pk.y = __builtin_amdgcn_perm(u3, u2, 0x07060302u);
      pk.z = __builtin_amdgcn_perm(u5, u4, 0x07060302u);
      pk.w = __builtin_amdgcn_perm(u7, u6, 0x07060302u);
      const short8 af = __builtin_bit_cast(short8, pk);
      const short* bk = bb + 1024;
      short8 b0 = *(const short8*)bk;
      short8 b1 = *(const short8*)(bk + 512);
      acc0 = __builtin_amdgcn_mfma_f32_16x16x32_bf16(af, b0, acc0, 0, 0, 0);
      acc1 = __builtin_amdgcn_mfma_f32_16x16x32_bf16(af, b1, acc1, 0, 0, 0);
      accz = __builtin_amdgcn_mfma_f32_16x16x32_bf16(af, vones, accz, 0, 0, 0);
    }
  }
  if (cl == 0) {
    #pragma unroll
    for (int reg = 0; reg < 4; ++reg) zsh[wid * 16 + q * 4 + reg] = accz[reg];
  }
  float4_ a01[2] = {acc0, acc1};
  #pragma unroll
  for (int nt = 0; nt < 2; ++nt)
    #pragma unroll
    for (int reg = 0; reg < 4; ++reg)
      accs[wid][q * 4 + reg][nt * 16 + cl] = a01[nt][reg];
  __syncthreads();
  #pragma unroll
  for (int r = 0; r < 2; ++r) {
    int o = r * 256 + t;
    int il = o >> 5, c = o & 31;
    float s = accs[0][il][c] + accs[1][il][c] + accs[2][il][c] + accs[3][il][c];
    float Z = zsh[il] + zsh[16 + il] + zsh[32 + il] + zsh[48 + il];
    outp[((long long)b * 2048 + i0 + il) * 32 + c] = s / Z;
  }
}

// ---------------------------------------------------------------------------
extern "C" void kernel_launch(void* const* d_in, const int* in_sizes, int n_in,
                              void* d_out, int out_size, void* d_ws, size_t ws_size,
                              hipStream_t stream) {
  const float* x   = (const float*)d_in[0];
  const int*   adj = (const int*)d_in[1];
  const float* W   = (const float*)d_in[2];
  const float* a1  = (const float*)d_in[3];
  const float* a2  = (const float*)d_in[4];
  const float* Wo  = (const float*)d_in[5];
  const float* ao1 = (const float*)d_in[6];
  const float* ao2 = (const float*)d_in[7];
  float* out = (float*)d_out;
  char* ws = (char*)d_ws;

  unsigned long long* maskb = (unsigned long long*)(ws + 0);          //  2 MB
  float* Wh   = (float*)(ws + 2097152);                               // 16 MB
  short* WhF  = (short*)(ws + 18874368);                              //  8 MB bf16 frags
  float* f1   = (float*)(ws + 27262976);
  float* f2   = (float*)(ws + 27525120);
  float* h1   = (float*)(ws + 27787264);                              // 16 MB
  float* Wh2  = (float*)(ws + 44564480);                              //  1 MB
  short* Wh2F = (short*)(ws + 45613056);                              //  0.5 MB
  float* g1   = (float*)(ws + 46137344);
  float* g2   = (float*)(ws + 46170112);

  hipLaunchKernelGGL(k_pack_mask, dim3(2048), dim3(256), 0, stream, adj, maskb);
  hipLaunchKernelGGL(k_wh, dim3(32, 32), dim3(256), 0, stream, x, W, Wh);
  hipLaunchKernelGGL((k_repack<64>), dim3(2048), dim3(256), 0, stream, Wh, WhF);
  hipLaunchKernelGGL(k_f12, dim3(16384), dim3(256), 0, stream, Wh, a1, a2, f1, f2);
  hipLaunchKernelGGL(k_attn1, dim3(32, 32), dim3(256), 0, stream, WhF, f1, f2, maskb, h1);
  hipLaunchKernelGGL(k_ogemm, dim3(256), dim3(256), 0, stream, h1, Wo, ao1, ao2, Wh2, g1, g2);
  hipLaunchKernelGGL((k_repack<32>), dim3(128), dim3(256), 0, stream, Wh2, Wh2F);
  hipLaunchKernelGGL(k_attn2, dim3(128, 4), dim3(256), 0, stream, Wh2F, g1, g2, maskb, out);
}